// Round 4
// baseline (467.546 us; speedup 1.0000x reference)
//
#include <hip/hip_runtime.h>
#include <hip/hip_bf16.h>

using bf16 = __hip_bfloat16;
typedef __attribute__((ext_vector_type(8))) short short8;   // 8 bf16 = 4 VGPRs (MFMA A/B frag)
typedef __attribute__((ext_vector_type(4))) float f32x4;    // MFMA C/D frag

// async global->LDS, 16B per lane; LDS dest = wave-uniform base + lane*16
#define GLL16(gp, lp) __builtin_amdgcn_global_load_lds( \
    (__attribute__((address_space(1))) void*)(gp),      \
    (__attribute__((address_space(3))) void*)(lp), 16, 0, 0)

__device__ __forceinline__ bf16 f2b(float x) { return __float2bfloat16(x); }
__device__ __forceinline__ float s2f(short x) {
  unsigned u = ((unsigned)(unsigned short)x) << 16;
  return __uint_as_float(u);
}
__device__ __forceinline__ short f2s(float x) {
  bf16 h = __float2bfloat16(x);
  return *reinterpret_cast<short*>(&h);
}

#define TRIG_C (1.5707963268f / 2048.0f)   // (pi/2)/len, len = T = S = 2048

// ---------------------------------------------------------------------------
// f32 -> bf16 elementwise convert, 8 elems/thread (2x float4 in, 1x 16B out)
// ---------------------------------------------------------------------------
__global__ void cvt_f32_bf16(const float* __restrict__ src, bf16* __restrict__ dst, int n8)
{
  const int i = blockIdx.x * 256 + threadIdx.x;
  if (i >= n8) return;
  const f32x4 a = ((const f32x4*)src)[i * 2];
  const f32x4 b = ((const f32x4*)src)[i * 2 + 1];
  short8 o;
#pragma unroll
  for (int j = 0; j < 4; ++j) { o[j] = f2s(a[j]); o[4 + j] = f2s(b[j]); }
  *(short8*)&dst[i * 8] = o;
}

// ---------------------------------------------------------------------------
// NT GEMM, 256x256 tile, BK=64, 512 thr (8 waves, 2M x 4N), double-buffered.
// R4: counted-vmcnt schedule (T4) — raw s_barrier + s_waitcnt vmcnt(8)
// instead of __syncthreads' vmcnt(0) drain. Each wave's 8 GLL16 of STAGE(t+1)
// stay in flight across both barriers and all of compute(t); vmcnt(8) at the
// next iter top confirms STAGE(t) landed (loads complete in order). T5
// setprio around MFMA clusters. T2 both-sides XOR swizzle on K-loop staging
// (R2: conflict-free). LDS-transpose epilogue (R3: WRITE_SIZE = exactly 32MB).
// MODE 0: q-proj -> Qh  (bh, 2048, 64) d-contig, relu(v*0.125)   [bf16 out]
// MODE 1: k-proj -> KhT (bh, 64, 2048) s-contig, relu(v)         [bf16 out]
// MODE 2: v-proj -> VhT (bh, 64, 2048) s-contig                  [bf16 out]
// MODE 3: o-proj -> out (16384, 1024)  row-major                 [f32 out]
// ---------------------------------------------------------------------------
template<int MODE>
__global__ __launch_bounds__(512, 2)
void proj_gemm(const bf16* __restrict__ A, const bf16* __restrict__ W,
               const float* __restrict__ bias, void* __restrict__ O)
{
  constexpr int K = 1024;
  constexpr int BK = 64;
  constexpr int NT = K / BK;                     // 16 K-steps
  extern __shared__ __align__(16) char smem[];   // 2 x (As 32KB | Bs 32KB) = 128KB
  bf16* lds = (bf16*)smem;

  const int tid = threadIdx.x;
  const int w = tid >> 6, l = tid & 63;
  const int quad = l >> 4, l16 = l & 15;
  const int lrow = l >> 3;                       // row-in-chunk 0..7
  const int scol = ((l & 7) ^ lrow) << 3;        // swizzled source col (bf16 idx)
  const int wm = w >> 2, wn = w & 3;             // 2 x 4 wave grid

  const int bid = blockIdx.x;
  const int xcd = bid & 7, idx = bid >> 3;
  const int ni = idx & 3;
  const int mi = xcd + 8 * (idx >> 2);           // 0..63
  const long mblk = (long)mi * 256;
  const int  nblk = ni * 256;

  const bf16* Ag = A + mblk * K;
  const bf16* Wg = W + (long)nblk * K;

  f32x4 acc[8][4] = {};

  // wave w stages A chunks w*4..w*4+3 (8 rows x 64 cols = 1KB each) + same for B
  // -> 8 GLL16 per wave per STAGE (this is the vmcnt(8) unit)
  auto STAGE = [&](int buf, int kt) {
    bf16* As = lds + buf * 32768;
    bf16* Bs = As + 16384;
#pragma unroll
    for (int i = 0; i < 4; ++i) {
      const int c = w * 4 + i;
      const int r = c * 8 + lrow;
      GLL16(Ag + (long)r * K + kt + scol, &As[c * 512]);
      GLL16(Wg + (long)r * K + kt + scol, &Bs[c * 512]);
    }
  };

  auto COMPUTE = [&](int buf) {
    const bf16* As = lds + buf * 32768;
    const bf16* Bs = As + 16384;
#pragma unroll
    for (int kk = 0; kk < BK; kk += 32) {
      const int ko8 = (kk + quad * 8) >> 3;      // 16B-block idx pre-xor
      short8 a[8], b[4];
#pragma unroll
      for (int sb = 0; sb < 8; ++sb) {
        const int row = wm * 128 + sb * 16 + l16;
        a[sb] = *(const short8*)&As[row * 64 + ((ko8 ^ (row & 7)) << 3)];
      }
#pragma unroll
      for (int u = 0; u < 4; ++u) {
        const int row = wn * 64 + u * 16 + l16;
        b[u] = *(const short8*)&Bs[row * 64 + ((ko8 ^ (row & 7)) << 3)];
      }
      __builtin_amdgcn_s_setprio(1);
#pragma unroll
      for (int sb = 0; sb < 8; ++sb)
#pragma unroll
        for (int u = 0; u < 4; ++u)
          acc[sb][u] = __builtin_amdgcn_mfma_f32_16x16x32_bf16(a[sb], b[u], acc[sb][u], 0, 0, 0);
      __builtin_amdgcn_s_setprio(0);
    }
  };

  STAGE(0, 0);
#pragma unroll 1
  for (int t = 0; t < NT - 1; ++t) {
    STAGE((t + 1) & 1, (t + 1) * BK);            // 8 loads, stay in flight
    asm volatile("s_waitcnt vmcnt(8)" ::: "memory");  // STAGE(t) landed
    __builtin_amdgcn_s_barrier();                // all waves: buf[t&1] full
    __builtin_amdgcn_sched_barrier(0);           // no ds_read hoisting above
    COMPUTE(t & 1);
    __builtin_amdgcn_s_barrier();                // all reads done -> safe overwrite
  }
  asm volatile("s_waitcnt vmcnt(0)" ::: "memory");    // last STAGE landed
  __builtin_amdgcn_s_barrier();
  __builtin_amdgcn_sched_barrier(0);
  COMPUTE((NT - 1) & 1);
  __syncthreads();   // full sync before LDS-transpose epilogue reuses all 128KB

  if (MODE == 3) {
    // direct f32 row-major stores: each quad writes a full 64B line
#pragma unroll
    for (int sb = 0; sb < 8; ++sb) {
      const int row0 = (int)mblk + wm * 128 + sb * 16 + quad * 4;
#pragma unroll
      for (int u = 0; u < 4; ++u) {
        const int col = nblk + wn * 64 + u * 16 + l16;
        const float bc = bias[col];
#pragma unroll
        for (int j = 0; j < 4; ++j)
          ((float*)O)[(long)(row0 + j) * 1024 + col] = acc[sb][u][j] + bc;
      }
    }
  } else {
    // ---- LDS-transpose epilogue (K-loop LDS is dead; 256x256 bf16 = 128KB) ----
    bf16* T = lds;
    // write phase: acc -> LDS in output-major layout
#pragma unroll
    for (int sb = 0; sb < 8; ++sb) {
#pragma unroll
      for (int u = 0; u < 4; ++u) {
        const int lc = wn * 64 + u * 16 + l16;   // 0..255
        const int h = lc >> 6, d = lc & 63;
        const float bc = bias[nblk + lc];
#pragma unroll
        for (int j = 0; j < 4; ++j) {
          const int lr = wm * 128 + sb * 16 + quad * 4 + j;   // 0..255
          float v = acc[sb][u][j] + bc;
          if (MODE == 0) v = fmaxf(v * 0.125f, 0.f);
          if (MODE == 1) v = fmaxf(v, 0.f);
          int ix;
          if (MODE == 0) {
            // layout [bb][h][tt][d], d-chunk XOR-swizzled by tt
            const int tt = lr >> 3, bb = lr & 7;
            const int dc = (d >> 3) ^ (tt & 7);
            ix = (((bb * 4 + h) * 32 + tt) * 8 + dc) * 8 + (d & 7);
          } else {
            // layout [bb][h][d][ss], s-chunk XOR-swizzled by d
            const int ss = lr >> 3, bb = lr & 7;
            const int sc = (ss >> 3) ^ (d & 3);
            ix = (((bb * 4 + h) * 64 + d) * 4 + sc) * 8 + (ss & 7);
          }
          T[ix] = f2b(v);
        }
      }
    }
    __syncthreads();
    // read phase: 16 x 16B chunks per thread; consecutive lanes cover full lines
    const int hbase = nblk >> 6;       // ni*4
    const int sbase = (int)(mblk >> 3);
#pragma unroll
    for (int i = 0; i < 16; ++i) {
      const int c = i * 512 + tid;     // 0..8191
      if (MODE == 0) {
        const int dch = c & 7, tt = (c >> 3) & 31, h = (c >> 8) & 3, bb = c >> 10;
        const short8 val = *(const short8*)&T[(((bb * 4 + h) * 32 + tt) * 8 + (dch ^ (tt & 7))) * 8];
        bf16* dst = (bf16*)O + ((long)(bb * 16 + hbase + h) * 2048 + sbase + tt) * 64 + dch * 8;
        *(short8*)dst = val;
      } else {
        const int sc = c & 3, d = (c >> 2) & 63, h = (c >> 8) & 3, bb = c >> 10;
        const short8 val = *(const short8*)&T[(((bb * 4 + h) * 64 + d) * 4 + (sc ^ (d & 3))) * 8];
        bf16* dst = (bf16*)O + ((long)(bb * 16 + hbase + h) * 64 + d) * 2048 + sbase + sc * 8;
        *(short8*)dst = val;
      }
    }
  }
}

// ---------------------------------------------------------------------------
// ksum2[bh*128 + d]      = sum_s sin_s * KhT[bh][d][s]
// ksum2[bh*128 + 64 + d] = sum_s cos_s * KhT[bh][d][s]
// ---------------------------------------------------------------------------
__global__ void ksum2_kernel(const bf16* __restrict__ KhT, float* __restrict__ ksum2)
{
  const int gw = (blockIdx.x * 256 + threadIdx.x) >> 6;   // 0..8191
  const int l = threadIdx.x & 63;
  const int bh = gw >> 6, d = gw & 63;
  const bf16* row = KhT + ((long)bh * 64 + d) * 2048;
  float ss = 0.f, cc = 0.f;
#pragma unroll
  for (int i = 0; i < 4; ++i) {
    short8 v = *(const short8*)&row[i * 512 + l * 8];
#pragma unroll
    for (int j = 0; j < 8; ++j) {
      const int s = i * 512 + l * 8 + j;
      const float ang = (float)(s + 1) * TRIG_C;
      const float f = s2f(v[j]);
      ss += f * __sinf(ang);
      cc += f * __cosf(ang);
    }
  }
#pragma unroll
  for (int off = 32; off > 0; off >>= 1) {
    ss += __shfl_down(ss, off);
    cc += __shfl_down(cc, off);
  }
  if (l == 0) {
    ksum2[bh * 128 + d]      = ss;
    ksum2[bh * 128 + 64 + d] = cc;
  }
}

// ---------------------------------------------------------------------------
// kv2[bh][f*64+e][d] = sum_s trig_f(s)*v[s,e]*k[s,d],  f=blockIdx.y (0=sin,1=cos)
// Per block: M=64 (e), N=64 (d), K=2048. Grid (128, 2).
// ---------------------------------------------------------------------------
__global__ void kv_gemm(const bf16* __restrict__ VhT, const bf16* __restrict__ KhT,
                        bf16* __restrict__ kv2)
{
  __shared__ __align__(16) bf16 As[64 * 64];
  __shared__ __align__(16) bf16 Bs[64 * 64];
  const int bh = blockIdx.x;
  const int fl = blockIdx.y;                       // 0=sin, 1=cos
  const int tid = threadIdx.x, w = tid >> 6, l = tid & 63;
  const int quad = l >> 4, l16 = l & 15;
  const int lrow = l >> 3, lcol = (l & 7) * 8;
  const bf16* Vg = VhT + (long)bh * 64 * 2048;
  const bf16* Kg = KhT + (long)bh * 64 * 2048;
  const int ar = tid >> 2, ac = (tid & 3) * 16;    // A-staging role

  f32x4 acc[4] = {};

  for (int kt = 0; kt < 2048; kt += 64) {
#pragma unroll
    for (int i = 0; i < 2; ++i) {                  // Bs: KhT rows d=0..63
      const int c = w * 2 + i, r = c * 8 + lrow;
      GLL16(Kg + (long)r * 2048 + kt + lcol, &Bs[c * 512]);
    }
    // As: load V tile 64x64, scale by this block's trig flavor
    short8 v0 = *(const short8*)&Vg[(long)ar * 2048 + kt + ac];
    short8 v1 = *(const short8*)&Vg[(long)ar * 2048 + kt + ac + 8];
    short8 o0, o1;
#pragma unroll
    for (int j = 0; j < 8; ++j) {
      const int sA = kt + ac + j, sB = sA + 8;
      const float angA = (float)(sA + 1) * TRIG_C, angB = (float)(sB + 1) * TRIG_C;
      const float wA = fl ? __cosf(angA) : __sinf(angA);
      const float wB = fl ? __cosf(angB) : __sinf(angB);
      o0[j] = f2s(s2f(v0[j]) * wA);
      o1[j] = f2s(s2f(v1[j]) * wB);
    }
    *(short8*)&As[ar * 64 + ac]     = o0;
    *(short8*)&As[ar * 64 + ac + 8] = o1;
    __syncthreads();
#pragma unroll
    for (int kk = 0; kk < 64; kk += 32) {
      const int ko = kk + quad * 8;
      short8 a = *(const short8*)&As[(w * 16 + l16) * 64 + ko];
      short8 b[4];
#pragma unroll
      for (int u = 0; u < 4; ++u) b[u] = *(const short8*)&Bs[(u * 16 + l16) * 64 + ko];
#pragma unroll
      for (int tn = 0; tn < 4; ++tn)
        acc[tn] = __builtin_amdgcn_mfma_f32_16x16x32_bf16(a, b[tn], acc[tn], 0, 0, 0);
    }
    __syncthreads();
  }
  bf16* out = kv2 + (long)bh * 128 * 64 + fl * 64 * 64;
#pragma unroll
  for (int tn = 0; tn < 4; ++tn) {
    const int d = tn * 16 + l16;
#pragma unroll
    for (int j = 0; j < 4; ++j) {
      const int e = w * 16 + quad * 4 + j;
      out[e * 64 + d] = f2b(acc[tn][j]);
    }
  }
}

// dinv[bh*2048+t] = 1 / max(sin_t*dot(qh, ks_sin) + cos_t*dot(qh, ks_cos), eps)
__global__ void den_kernel(const bf16* __restrict__ Qh, const float* __restrict__ ksum2,
                           float* __restrict__ dinv)
{
  __shared__ float ks[128];
  const int bh = blockIdx.y;
  const int t = blockIdx.x * 256 + threadIdx.x;
  if (threadIdx.x < 128) ks[threadIdx.x] = ksum2[bh * 128 + threadIdx.x];
  __syncthreads();
  const bf16* q = Qh + ((long)bh * 2048 + t) * 64;
  float d1 = 0.f, d2 = 0.f;
#pragma unroll
  for (int i = 0; i < 8; ++i) {
    short8 v = *(const short8*)&q[i * 8];
#pragma unroll
    for (int j = 0; j < 8; ++j) {
      const float f = s2f(v[j]);
      d1 += f * ks[i * 8 + j];
      d2 += f * ks[64 + i * 8 + j];
    }
  }
  const float ang = (float)(t + 1) * TRIG_C;
  const float den = __sinf(ang) * d1 + __cosf(ang) * d2;
  dinv[bh * 2048 + t] = 1.f / fmaxf(den, 1e-6f);
}

// att[(t*8+b)*1024 + h*64+e] = (sin_t*(Qh.kv2_sin^T) + cos_t*(Qh.kv2_cos^T)) * dinv
__global__ void attn_out(const bf16* __restrict__ Qh, const bf16* __restrict__ kv2,
                         const float* __restrict__ dinv, bf16* __restrict__ att)
{
  __shared__ __align__(16) bf16 Qs[128 * 64];
  __shared__ __align__(16) bf16 Ks[128 * 64];
  const int bh = blockIdx.y;
  const int t0 = blockIdx.x * 128;
  const int tid = threadIdx.x, w = tid >> 6, l = tid & 63;
  const int quad = l >> 4, l16 = l & 15;
  const int lrow = l >> 3, lcol = (l & 7) * 8;
  const bf16* Qg = Qh + ((long)bh * 2048 + t0) * 64;
  const bf16* Kg = kv2 + (long)bh * 128 * 64;
#pragma unroll
  for (int i = 0; i < 4; ++i) {
    const int c = w * 4 + i, r = c * 8 + lrow;
    GLL16(Qg + (long)r * 64 + lcol, &Qs[c * 512]);
  }
#pragma unroll
  for (int i = 0; i < 4; ++i) {
    const int c = w * 4 + i, r = c * 8 + lrow;
    GLL16(Kg + (long)r * 64 + lcol, &Ks[c * 512]);
  }
  __syncthreads();

  f32x4 accs[2][4] = {}, accc[2][4] = {};
#pragma unroll
  for (int kk = 0; kk < 64; kk += 32) {
    const int ko = kk + quad * 8;
    short8 a[2], bs[4], bc[4];
#pragma unroll
    for (int u = 0; u < 2; ++u) a[u] = *(const short8*)&Qs[(w * 32 + u * 16 + l16) * 64 + ko];
#pragma unroll
    for (int u = 0; u < 4; ++u) {
      bs[u] = *(const short8*)&Ks[(u * 16 + l16) * 64 + ko];
      bc[u] = *(const short8*)&Ks[(64 + u * 16 + l16) * 64 + ko];
    }
#pragma unroll
    for (int tm = 0; tm < 2; ++tm)
#pragma unroll
      for (int tn = 0; tn < 4; ++tn) {
        accs[tm][tn] = __builtin_amdgcn_mfma_f32_16x16x32_bf16(a[tm], bs[tn], accs[tm][tn], 0, 0, 0);
        accc[tm][tn] = __builtin_amdgcn_mfma_f32_16x16x32_bf16(a[tm], bc[tn], accc[tm][tn], 0, 0, 0);
      }
  }
  const int bb = bh >> 4, h = bh & 15;
#pragma unroll
  for (int tm = 0; tm < 2; ++tm)
#pragma unroll
    for (int j = 0; j < 4; ++j) {
      const int tr = w * 32 + tm * 16 + quad * 4 + j;
      const int t = t0 + tr;
      const float di = dinv[bh * 2048 + t];
      const float ang = (float)(t + 1) * TRIG_C;
      const float sn = __sinf(ang), cs = __cosf(ang);
#pragma unroll
      for (int tn = 0; tn < 4; ++tn) {
        const int e = tn * 16 + l16;
        const float v = (sn * accs[tm][tn][j] + cs * accc[tm][tn][j]) * di;
        att[((long)t * 8 + bb) * 1024 + h * 64 + e] = f2b(v);
      }
    }
}

extern "C" void kernel_launch(void* const* d_in, const int* in_sizes, int n_in,
                              void* d_out, int out_size, void* d_ws, size_t ws_size,
                              hipStream_t stream)
{
  const float* query  = (const float*)d_in[0];
  const float* key_in = (const float*)d_in[1];
  const float* value  = (const float*)d_in[2];
  const float* wq = (const float*)d_in[3];  const float* bq = (const float*)d_in[4];
  const float* wk = (const float*)d_in[5];  const float* bk = (const float*)d_in[6];
  const float* wv = (const float*)d_in[7];  const float* bv = (const float*)d_in[8];
  const float* wo = (const float*)d_in[9];  const float* bo = (const float*)d_in[10];

  // ws layout (37.06 MB total, within the proven available size):
  char* ws = (char*)d_ws;
  float* ksum2 = (float*)(ws);                 // 64 KB
  float* dinv  = (float*)(ws + 65536);         // 1 MB
  bf16*  kv2   = (bf16*)(ws + 1114112);        // 2 MB
  bf16*  Wslot = (bf16*)(ws + 3211264);        // 2 MB (Wk -> Wv -> Wq -> Wo)
  bf16*  R1    = (bf16*)(ws + 5308416);        // 32 MB (KhT -> ATT)
  bf16*  KhT = R1, *ATT = R1;
  // d_out (64 MB f32) time-multiplexed as two 32 MB bf16 regions:
  bf16*  D1 = (bf16*)d_out;                    // Kbf -> VhT -> Qh
  bf16*  D2 = (bf16*)d_out + 16777216;         // Vbf -> Qbf
  // final proj_gemm<3> writes f32 over D1+D2 (both dead by then)

  // 128KB dynamic LDS for the 2-phase double-buffered proj_gemm
  const int PROJ_LDS = 131072;
  hipFuncSetAttribute((const void*)&proj_gemm<0>, hipFuncAttributeMaxDynamicSharedMemorySize, PROJ_LDS);
  hipFuncSetAttribute((const void*)&proj_gemm<1>, hipFuncAttributeMaxDynamicSharedMemorySize, PROJ_LDS);
  hipFuncSetAttribute((const void*)&proj_gemm<2>, hipFuncAttributeMaxDynamicSharedMemorySize, PROJ_LDS);
  hipFuncSetAttribute((const void*)&proj_gemm<3>, hipFuncAttributeMaxDynamicSharedMemorySize, PROJ_LDS);

  dim3 blk(256);
  dim3 pblk(512);
  dim3 gproj(256);                                     // 64 mi x 4 ni
  const int nBig = 16777216 / 8, gBig = nBig / 256;    // inputs: 8192 blocks
  const int nW   = 1048576 / 8,  gW   = nW / 256;      // weights: 512 blocks

  // K path
  hipLaunchKernelGGL(cvt_f32_bf16, dim3(gBig), blk, 0, stream, key_in, D1, nBig);
  hipLaunchKernelGGL(cvt_f32_bf16, dim3(gW),   blk, 0, stream, wk, Wslot, nW);
  hipLaunchKernelGGL((proj_gemm<1>), gproj, pblk, PROJ_LDS, stream, D1, Wslot, bk, KhT);
  hipLaunchKernelGGL(ksum2_kernel, dim3(2048), blk, 0, stream, KhT, ksum2);
  // V path
  hipLaunchKernelGGL(cvt_f32_bf16, dim3(gBig), blk, 0, stream, value, D2, nBig);
  hipLaunchKernelGGL(cvt_f32_bf16, dim3(gW),   blk, 0, stream, wv, Wslot, nW);
  hipLaunchKernelGGL((proj_gemm<2>), gproj, pblk, PROJ_LDS, stream, D2, Wslot, bv, D1); // VhT=D1
  hipLaunchKernelGGL(kv_gemm, dim3(128, 2), blk, 0, stream, D1, KhT, kv2);
  // Q path
  hipLaunchKernelGGL(cvt_f32_bf16, dim3(gBig), blk, 0, stream, query, D2, nBig);
  hipLaunchKernelGGL(cvt_f32_bf16, dim3(gW),   blk, 0, stream, wq, Wslot, nW);
  hipLaunchKernelGGL((proj_gemm<0>), gproj, pblk, PROJ_LDS, stream, D2, Wslot, bq, D1); // Qh=D1
  hipLaunchKernelGGL(den_kernel, dim3(8, 128), blk, 0, stream, D1, ksum2, dinv);
  hipLaunchKernelGGL(attn_out, dim3(16, 128), blk, 0, stream, D1, kv2, dinv, ATT);
  // O path
  hipLaunchKernelGGL(cvt_f32_bf16, dim3(gW),   blk, 0, stream, wo, Wslot, nW);
  hipLaunchKernelGGL((proj_gemm<3>), gproj, pblk, PROJ_LDS, stream, ATT, Wslot, bo, d_out);
}

// Round 6
// 439.069 us; speedup vs baseline: 1.0649x; 1.0649x over previous
//
#include <hip/hip_runtime.h>
#include <hip/hip_bf16.h>

using bf16 = __hip_bfloat16;
typedef __attribute__((ext_vector_type(8))) short short8;   // 8 bf16 = 4 VGPRs (MFMA A/B frag)
typedef __attribute__((ext_vector_type(4))) float f32x4;    // MFMA C/D frag

// async global->LDS, 16B per lane; LDS dest = wave-uniform base + lane*16
#define GLL16(gp, lp) __builtin_amdgcn_global_load_lds( \
    (__attribute__((address_space(1))) void*)(gp),      \
    (__attribute__((address_space(3))) void*)(lp), 16, 0, 0)

__device__ __forceinline__ bf16 f2b(float x) { return __float2bfloat16(x); }
__device__ __forceinline__ float s2f(short x) {
  unsigned u = ((unsigned)(unsigned short)x) << 16;
  return __uint_as_float(u);
}
__device__ __forceinline__ short f2s(float x) {
  bf16 h = __float2bfloat16(x);
  return *reinterpret_cast<short*>(&h);
}

#define TRIG_C (1.5707963268f / 2048.0f)   // (pi/2)/len, len = T = S = 2048

// ---------------------------------------------------------------------------
// f32 -> bf16 elementwise convert, 8 elems/thread (2x float4 in, 1x 16B out)
// ---------------------------------------------------------------------------
__global__ void cvt_f32_bf16(const float* __restrict__ src, bf16* __restrict__ dst, int n8)
{
  const int i = blockIdx.x * 256 + threadIdx.x;
  if (i >= n8) return;
  const f32x4 a = ((const f32x4*)src)[i * 2];
  const f32x4 b = ((const f32x4*)src)[i * 2 + 1];
  short8 o;
#pragma unroll
  for (int j = 0; j < 4; ++j) { o[j] = f2s(a[j]); o[4 + j] = f2s(b[j]); }
  *(short8*)&dst[i * 8] = o;
}

// ---------------------------------------------------------------------------
// NT GEMM, 256x256 tile, BK=64, 512 thr (8 waves, 2M x 4N), double-buffered
// 2-phase prefetch (R3 structure, 43.7us measured; R4's 2-barrier counted-
// vmcnt variant REGRESSED to 54.5us -> exact revert). T2 both-sides XOR
// swizzle on staging (R2: conflict-free). LDS-transpose epilogue (R3:
// WRITE_SIZE = exactly 32MB, no RMW amplification).
// MODE 0: q-proj -> Qh  (bh, 2048, 64) d-contig, relu(v*0.125)   [bf16 out]
// MODE 1: k-proj -> KhT (bh, 64, 2048) s-contig, relu(v)         [bf16 out]
// MODE 2: v-proj -> VhT (bh, 64, 2048) s-contig                  [bf16 out]
// MODE 3: o-proj -> out (16384, 1024)  row-major                 [f32 out]
// ---------------------------------------------------------------------------
template<int MODE>
__global__ __launch_bounds__(512, 2)
void proj_gemm(const bf16* __restrict__ A, const bf16* __restrict__ W,
               const float* __restrict__ bias, void* __restrict__ O)
{
  constexpr int K = 1024;
  constexpr int BK = 64;
  extern __shared__ __align__(16) char smem[];   // 2 x (As 32KB | Bs 32KB) = 128KB
  bf16* lds = (bf16*)smem;

  const int tid = threadIdx.x;
  const int w = tid >> 6, l = tid & 63;
  const int quad = l >> 4, l16 = l & 15;
  const int lrow = l >> 3;                       // row-in-chunk 0..7
  const int scol = ((l & 7) ^ lrow) << 3;        // swizzled source col (bf16 idx)
  const int wm = w >> 2, wn = w & 3;             // 2 x 4 wave grid

  const int bid = blockIdx.x;
  const int xcd = bid & 7, idx = bid >> 3;
  const int ni = idx & 3;
  const int mi = xcd + 8 * (idx >> 2);           // 0..63
  const long mblk = (long)mi * 256;
  const int  nblk = ni * 256;
  const bf16* Ag = A + mblk * K;
  const bf16* Wg = W + (long)nblk * K;

  f32x4 acc[8][4] = {};

  auto STAGE = [&](int buf, int kt) {
    bf16* As = lds + buf * 32768;
    bf16* Bs = As + 16384;
#pragma unroll
    for (int i = 0; i < 4; ++i) {
      const int c = w * 4 + i;
      const int r = c * 8 + lrow;
      GLL16(Ag + (long)r * K + kt + scol, &As[c * 512]);
      GLL16(Wg + (long)r * K + kt + scol, &Bs[c * 512]);
    }
  };

  STAGE(0, 0);
  __syncthreads();

  for (int t = 0; t < K / BK; ++t) {
    if (t + 1 < K / BK) STAGE((t + 1) & 1, (t + 1) * BK);
    const bf16* As = lds + (t & 1) * 32768;
    const bf16* Bs = As + 16384;
#pragma unroll
    for (int kk = 0; kk < BK; kk += 32) {
      const int ko8 = (kk + quad * 8) >> 3;      // 16B-block idx pre-xor
      short8 a[8], b[4];
#pragma unroll
      for (int sb = 0; sb < 8; ++sb) {
        const int row = wm * 128 + sb * 16 + l16;
        a[sb] = *(const short8*)&As[row * 64 + ((ko8 ^ (row & 7)) << 3)];
      }
#pragma unroll
      for (int u = 0; u < 4; ++u) {
        const int row = wn * 64 + u * 16 + l16;
        b[u] = *(const short8*)&Bs[row * 64 + ((ko8 ^ (row & 7)) << 3)];
      }
#pragma unroll
      for (int sb = 0; sb < 8; ++sb)
#pragma unroll
        for (int u = 0; u < 4; ++u)
          acc[sb][u] = __builtin_amdgcn_mfma_f32_16x16x32_bf16(a[sb], b[u], acc[sb][u], 0, 0, 0);
    }
    __syncthreads();   // drains vmcnt -> buf[(t+1)&1] landed; buf[t&1] reads done
  }

  if (MODE == 3) {
    // direct f32 row-major stores: each quad writes a full 64B line
#pragma unroll
    for (int sb = 0; sb < 8; ++sb) {
      const int row0 = (int)mblk + wm * 128 + sb * 16 + quad * 4;
#pragma unroll
      for (int u = 0; u < 4; ++u) {
        const int col = nblk + wn * 64 + u * 16 + l16;
        const float bc = bias[col];
#pragma unroll
        for (int j = 0; j < 4; ++j)
          ((float*)O)[(long)(row0 + j) * 1024 + col] = acc[sb][u][j] + bc;
      }
    }
  } else {
    // ---- LDS-transpose epilogue (K-loop LDS is dead; 256x256 bf16 = 128KB) ----
    bf16* T = lds;
#pragma unroll
    for (int sb = 0; sb < 8; ++sb) {
#pragma unroll
      for (int u = 0; u < 4; ++u) {
        const int lc = wn * 64 + u * 16 + l16;   // 0..255
        const int h = lc >> 6, d = lc & 63;
        const float bc = bias[nblk + lc];
#pragma unroll
        for (int j = 0; j < 4; ++j) {
          const int lr = wm * 128 + sb * 16 + quad * 4 + j;   // 0..255
          float v = acc[sb][u][j] + bc;
          if (MODE == 0) v = fmaxf(v * 0.125f, 0.f);
          if (MODE == 1) v = fmaxf(v, 0.f);
          int ix;
          if (MODE == 0) {
            const int tt = lr >> 3, bb = lr & 7;
            const int dc = (d >> 3) ^ (tt & 7);
            ix = (((bb * 4 + h) * 32 + tt) * 8 + dc) * 8 + (d & 7);
          } else {
            const int ss = lr >> 3, bb = lr & 7;
            const int sc = (ss >> 3) ^ (d & 3);
            ix = (((bb * 4 + h) * 64 + d) * 4 + sc) * 8 + (ss & 7);
          }
          T[ix] = f2b(v);
        }
      }
    }
    __syncthreads();
    const int hbase = nblk >> 6;       // ni*4
    const int sbase = (int)(mblk >> 3);
#pragma unroll
    for (int i = 0; i < 16; ++i) {
      const int c = i * 512 + tid;     // 0..8191
      if (MODE == 0) {
        const int dch = c & 7, tt = (c >> 3) & 31, h = (c >> 8) & 3, bb = c >> 10;
        const short8 val = *(const short8*)&T[(((bb * 4 + h) * 32 + tt) * 8 + (dch ^ (tt & 7))) * 8];
        bf16* dst = (bf16*)O + ((long)(bb * 16 + hbase + h) * 2048 + sbase + tt) * 64 + dch * 8;
        *(short8*)dst = val;
      } else {
        const int sc = c & 3, d = (c >> 2) & 63, h = (c >> 8) & 3, bb = c >> 10;
        const short8 val = *(const short8*)&T[(((bb * 4 + h) * 64 + d) * 4 + (sc ^ (d & 3))) * 8];
        bf16* dst = (bf16*)O + ((long)(bb * 16 + hbase + h) * 64 + d) * 2048 + sbase + sc * 8;
        *(short8*)dst = val;
      }
    }
  }
}

// ---------------------------------------------------------------------------
// kv_gemm (R5): single source of kv2 AND ksum2. Flavor-split grid (128,2).
// K (not V) is trig-scaled during staging -> per-flavor ksum[d] falls out of
// the stager (each thread owns one d-row) via 4-lane shfl reduce.
// V staged raw via GLL16 (pre-swizzled source); K reg-staged: loads issued
// BEFORE compute (T14), sincos+swizzled ds_write after. 1 barrier/iter.
// T2 XOR swizzle on all tiles -> conflict-free fragment reads.
// kv2[bh][f*64+e][d] = sum_s trig_f(s)*v[s,e]*k[s,d]
// ksum2[bh*128 + f*64 + d] = sum_s trig_f(s)*k[s,d]
// ---------------------------------------------------------------------------
__global__ void kv_gemm(const bf16* __restrict__ VhT, const bf16* __restrict__ KhT,
                        bf16* __restrict__ kv2, float* __restrict__ ksum2)
{
  __shared__ __align__(16) bf16 Vs[2][64 * 64];
  __shared__ __align__(16) bf16 Ks[2][64 * 64];
  const int bh = blockIdx.x;
  const int fl = blockIdx.y;                       // 0=sin, 1=cos
  const int tid = threadIdx.x, w = tid >> 6, l = tid & 63;
  const int quad = l >> 4, l16 = l & 15;
  const int lrow = l >> 3;
  const int scol = ((l & 7) ^ lrow) << 3;          // pre-swizzled GLL16 source col
  const bf16* Vg = VhT + (long)bh * 64 * 2048;
  const bf16* Kg = KhT + (long)bh * 64 * 2048;
  const int ar = tid >> 2, ac8 = (tid & 3) * 2;    // K-stager: row ar, 16B-blocks ac8, ac8+1
  const int r7 = ar & 7;

  f32x4 acc[4] = {};
  float ps = 0.f;

  auto VSTAGE = [&](int buf, int kt) {
#pragma unroll
    for (int i = 0; i < 2; ++i) {
      const int c = w * 2 + i, r = c * 8 + lrow;
      GLL16(Vg + (long)r * 2048 + kt + scol, &Vs[buf][c * 512]);
    }
  };
  auto KLOAD = [&](int kt, short8& ka, short8& kb) {
    ka = *(const short8*)&Kg[(long)ar * 2048 + kt + ac8 * 8];
    kb = *(const short8*)&Kg[(long)ar * 2048 + kt + ac8 * 8 + 8];
  };
  auto KSCALE = [&](int buf, int kt, short8 ka, short8 kb) {
    short8 o0, o1;
#pragma unroll
    for (int j = 0; j < 8; ++j) {
      const int sA = kt + ac8 * 8 + j, sB = sA + 8;
      const float angA = (float)(sA + 1) * TRIG_C, angB = (float)(sB + 1) * TRIG_C;
      const float wA = fl ? __cosf(angA) : __sinf(angA);
      const float wB = fl ? __cosf(angB) : __sinf(angB);
      const float fA = s2f(ka[j]), fB = s2f(kb[j]);
      o0[j] = f2s(fA * wA);  o1[j] = f2s(fB * wB);
      ps += fA * wA + fB * wB;
    }
    *(short8*)&Ks[buf][ar * 64 + ((ac8 ^ r7) << 3)]       = o0;
    *(short8*)&Ks[buf][ar * 64 + (((ac8 + 1) ^ r7) << 3)] = o1;
  };

  { short8 ka, kb; KLOAD(0, ka, kb); VSTAGE(0, 0); KSCALE(0, 0, ka, kb); }
  __syncthreads();

  for (int t = 0; t < 32; ++t) {
    short8 ka, kb;
    if (t < 31) { KLOAD((t + 1) * 64, ka, kb); VSTAGE((t + 1) & 1, (t + 1) * 64); }
    const int buf = t & 1;
#pragma unroll
    for (int kk = 0; kk < 64; kk += 32) {
      const int ko8 = (kk + quad * 8) >> 3;
      const int rowa = w * 16 + l16;
      short8 a = *(const short8*)&Vs[buf][rowa * 64 + ((ko8 ^ (l16 & 7)) << 3)];
      short8 b[4];
#pragma unroll
      for (int u = 0; u < 4; ++u)
        b[u] = *(const short8*)&Ks[buf][(u * 16 + l16) * 64 + ((ko8 ^ (l16 & 7)) << 3)];
#pragma unroll
      for (int tn = 0; tn < 4; ++tn)
        acc[tn] = __builtin_amdgcn_mfma_f32_16x16x32_bf16(a, b[tn], acc[tn], 0, 0, 0);
    }
    if (t < 31) KSCALE((t + 1) & 1, (t + 1) * 64, ka, kb);
    __syncthreads();   // drains GLL16 vmcnt + ds_writes; publishes buf (t+1)&1
  }

  bf16* out = kv2 + (long)bh * 128 * 64 + fl * 64 * 64;
#pragma unroll
  for (int tn = 0; tn < 4; ++tn) {
    const int d = tn * 16 + l16;
#pragma unroll
    for (int j = 0; j < 4; ++j) {
      const int e = w * 16 + quad * 4 + j;
      out[e * 64 + d] = f2b(acc[tn][j]);
    }
  }
  // ksum: 4 stager-lanes per d-row share via xor-shuffle
  ps += __shfl_xor(ps, 1);
  ps += __shfl_xor(ps, 2);
  if ((tid & 3) == 0) ksum2[bh * 128 + fl * 64 + ar] = ps;
}

// ---------------------------------------------------------------------------
// attn_out (R5): den fused in (f32 VALU on the staged Q tile, identical
// numerics to the old den_kernel). T2 swizzled staging + reads.
// att[(t*8+b)*1024 + h*64+e] = (sin_t*(Qh.kv2_sin^T)+cos_t*(Qh.kv2_cos^T))/den
// ---------------------------------------------------------------------------
__global__ void attn_out(const bf16* __restrict__ Qh, const bf16* __restrict__ kv2,
                         const float* __restrict__ ksum2g, bf16* __restrict__ att)
{
  __shared__ __align__(16) bf16 Qs[128 * 64];
  __shared__ __align__(16) bf16 Ks[128 * 64];
  __shared__ float ks[128];
  __shared__ float dinv_s[128];
  const int bh = blockIdx.y;
  const int t0 = blockIdx.x * 128;
  const int tid = threadIdx.x, w = tid >> 6, l = tid & 63;
  const int quad = l >> 4, l16 = l & 15;
  const int lrow = l >> 3;
  const int scol = ((l & 7) ^ lrow) << 3;
  const bf16* Qg = Qh + ((long)bh * 2048 + t0) * 64;
  const bf16* Kg = kv2 + (long)bh * 128 * 64;
#pragma unroll
  for (int i = 0; i < 4; ++i) {
    const int c = w * 4 + i, r = c * 8 + lrow;
    GLL16(Qg + (long)r * 64 + scol, &Qs[c * 512]);
  }
#pragma unroll
  for (int i = 0; i < 4; ++i) {
    const int c = w * 4 + i, r = c * 8 + lrow;
    GLL16(Kg + (long)r * 64 + scol, &Ks[c * 512]);
  }
  if (tid < 128) ks[tid] = ksum2g[bh * 128 + tid];
  __syncthreads();

  // ---- fused den: row r = tid>>1, d-half = tid&1 (f32, like old den_kernel) ----
  {
    const int r = tid >> 1, half = tid & 1;
    float d1 = 0.f, d2 = 0.f;
#pragma unroll
    for (int blk = 0; blk < 4; ++blk) {
      const int g = (half * 4 + blk) ^ (r & 7);          // unswizzle
      const short8 v = *(const short8*)&Qs[r * 64 + g * 8];
#pragma unroll
      for (int j = 0; j < 8; ++j) {
        const float f = s2f(v[j]);
        const int d = half * 32 + blk * 8 + j;
        d1 += f * ks[d];
        d2 += f * ks[64 + d];
      }
    }
    d1 += __shfl_xor(d1, 1);
    d2 += __shfl_xor(d2, 1);
    if (half == 0) {
      const float ang = (float)(t0 + r + 1) * TRIG_C;
      const float den = __sinf(ang) * d1 + __cosf(ang) * d2;
      dinv_s[r] = 1.f / fmaxf(den, 1e-6f);
    }
  }

  f32x4 accs[2][4] = {}, accc[2][4] = {};
#pragma unroll
  for (int kk = 0; kk < 64; kk += 32) {
    const int ko8 = (kk + quad * 8) >> 3;
    short8 a[2], bs[4], bc[4];
#pragma unroll
    for (int u = 0; u < 2; ++u) {
      const int row = w * 32 + u * 16 + l16;
      a[u] = *(const short8*)&Qs[row * 64 + ((ko8 ^ (row & 7)) << 3)];
    }
#pragma unroll
    for (int u = 0; u < 4; ++u) {
      bs[u] = *(const short8*)&Ks[(u * 16 + l16) * 64 + ((ko8 ^ (l16 & 7)) << 3)];
      bc[u] = *(const short8*)&Ks[(64 + u * 16 + l16) * 64 + ((ko8 ^ (l16 & 7)) << 3)];
    }
#pragma unroll
    for (int tm = 0; tm < 2; ++tm)
#pragma unroll
      for (int tn = 0; tn < 4; ++tn) {
        accs[tm][tn] = __builtin_amdgcn_mfma_f32_16x16x32_bf16(a[tm], bs[tn], accs[tm][tn], 0, 0, 0);
        accc[tm][tn] = __builtin_amdgcn_mfma_f32_16x16x32_bf16(a[tm], bc[tn], accc[tm][tn], 0, 0, 0);
      }
  }
  __syncthreads();   // dinv_s written by all threads before epilogue reads

  const int bb = bh >> 4, h = bh & 15;
#pragma unroll
  for (int tm = 0; tm < 2; ++tm)
#pragma unroll
    for (int j = 0; j < 4; ++j) {
      const int tr = w * 32 + tm * 16 + quad * 4 + j;
      const int t = t0 + tr;
      const float di = dinv_s[tr];
      const float ang = (float)(t + 1) * TRIG_C;
      const float sn = __sinf(ang), cs = __cosf(ang);
#pragma unroll
      for (int tn = 0; tn < 4; ++tn) {
        const int e = tn * 16 + l16;
        const float v = (sn * accs[tm][tn][j] + cs * accc[tm][tn][j]) * di;
        att[((long)t * 8 + bb) * 1024 + h * 64 + e] = f2b(v);
      }
    }
}

extern "C" void kernel_launch(void* const* d_in, const int* in_sizes, int n_in,
                              void* d_out, int out_size, void* d_ws, size_t ws_size,
                              hipStream_t stream)
{
  const float* query  = (const float*)d_in[0];
  const float* key_in = (const float*)d_in[1];
  const float* value  = (const float*)d_in[2];
  const float* wq = (const float*)d_in[3];  const float* bq = (const float*)d_in[4];
  const float* wk = (const float*)d_in[5];  const float* bk = (const float*)d_in[6];
  const float* wv = (const float*)d_in[7];  const float* bv = (const float*)d_in[8];
  const float* wo = (const float*)d_in[9];  const float* bo = (const float*)d_in[10];

  // ws layout (37.06 MB total):
  char* ws = (char*)d_ws;
  float* ksum2 = (float*)(ws);                 // 64 KB
  bf16*  kv2   = (bf16*)(ws + 1114112);        // 2 MB
  bf16*  Wslot = (bf16*)(ws + 3211264);        // 2 MB (Wk -> Wv -> Wq -> Wo)
  bf16*  R1    = (bf16*)(ws + 5308416);        // 32 MB (KhT -> ATT)
  bf16*  KhT = R1, *ATT = R1;
  // d_out (64 MB f32) time-multiplexed as two 32 MB bf16 regions:
  bf16*  D1 = (bf16*)d_out;                    // Kbf -> VhT -> Qh
  bf16*  D2 = (bf16*)d_out + 16777216;         // Vbf -> Qbf

  const int PROJ_LDS = 131072;
  hipFuncSetAttribute((const void*)&proj_gemm<0>, hipFuncAttributeMaxDynamicSharedMemorySize, PROJ_LDS);
  hipFuncSetAttribute((const void*)&proj_gemm<1>, hipFuncAttributeMaxDynamicSharedMemorySize, PROJ_LDS);
  hipFuncSetAttribute((const void*)&proj_gemm<2>, hipFuncAttributeMaxDynamicSharedMemorySize, PROJ_LDS);
  hipFuncSetAttribute((const void*)&proj_gemm<3>, hipFuncAttributeMaxDynamicSharedMemorySize, PROJ_LDS);

  dim3 blk(256);
  dim3 pblk(512);
  dim3 gproj(256);                                     // 64 mi x 4 ni
  const int nBig = 16777216 / 8, gBig = nBig / 256;    // inputs: 8192 blocks
  const int nW   = 1048576 / 8,  gW   = nW / 256;      // weights: 512 blocks

  // K path
  hipLaunchKernelGGL(cvt_f32_bf16, dim3(gBig), blk, 0, stream, key_in, D1, nBig);
  hipLaunchKernelGGL(cvt_f32_bf16, dim3(gW),   blk, 0, stream, wk, Wslot, nW);
  hipLaunchKernelGGL((proj_gemm<1>), gproj, pblk, PROJ_LDS, stream, D1, Wslot, bk, KhT);
  // V path
  hipLaunchKernelGGL(cvt_f32_bf16, dim3(gBig), blk, 0, stream, value, D2, nBig);
  hipLaunchKernelGGL(cvt_f32_bf16, dim3(gW),   blk, 0, stream, wv, Wslot, nW);
  hipLaunchKernelGGL((proj_gemm<2>), gproj, pblk, PROJ_LDS, stream, D2, Wslot, bv, D1); // VhT=D1
  hipLaunchKernelGGL(kv_gemm, dim3(128, 2), blk, 0, stream, D1, KhT, kv2, ksum2);
  // Q path
  hipLaunchKernelGGL(cvt_f32_bf16, dim3(gBig), blk, 0, stream, query, D2, nBig);
  hipLaunchKernelGGL(cvt_f32_bf16, dim3(gW),   blk, 0, stream, wq, Wslot, nW);
  hipLaunchKernelGGL((proj_gemm<0>), gproj, pblk, PROJ_LDS, stream, D2, Wslot, bq, D1); // Qh=D1
  hipLaunchKernelGGL(attn_out, dim3(16, 128), blk, 0, stream, D1, kv2, ksum2, ATT);
  // O path
  hipLaunchKernelGGL(cvt_f32_bf16, dim3(gW),   blk, 0, stream, wo, Wslot, nW);
  hipLaunchKernelGGL((proj_gemm<3>), gproj, pblk, PROJ_LDS, stream, ATT, Wslot, bo, d_out);
}